// Round 1
// baseline (245.551 us; speedup 1.0000x reference)
//
#include <hip/hip_runtime.h>
#include <hip/hip_bf16.h>
#include <stdint.h>
#include <math.h>

#define EPSV 1e-7f
#define B_   8
#define CIN  512
#define COUT 512
#define HH   64
#define WW   64
#define SS   512
#define HP   66
#define WP   66
#define NP   (HH*WW)   // 4096 spatial

typedef __attribute__((ext_vector_type(8))) short bf16x8;
typedef __attribute__((ext_vector_type(4))) float f32x4;

// ---------------- kernel 1: s = style @ mod_w^T + mod_b  (8x512) -------------
__global__ __launch_bounds__(256) void k_style(const float* __restrict__ style,
                                               const float* __restrict__ mod_w,
                                               const float* __restrict__ mod_b,
                                               float* __restrict__ s_out) {
    int id = blockIdx.x * 256 + threadIdx.x;   // 4096 outputs
    int b = id >> 9, ci = id & 511;
    float acc = mod_b[ci];
    const float* st = style + (size_t)b * SS;
    const float* mw = mod_w + (size_t)ci * SS;
    for (int k = 0; k < SS; ++k) acc += st[k] * mw[k];
    s_out[id] = acc;
}

// -------- kernel 2: modulate + demod weights -> bf16 wmod[b][t][co][ci] ------
__global__ __launch_bounds__(256) void k_wmod(const float* __restrict__ weight,
                                              const float* __restrict__ s_in,
                                              __hip_bfloat16* __restrict__ wmod) {
    int b  = blockIdx.x >> 9;
    int co = blockIdx.x & 511;
    int tid = threadIdx.x;
    const float scale = (float)(1.0 / sqrt(4608.0));  // 1/sqrt(Cin*K*K)
    float m[2][9];
    float sq = 0.f;
    #pragma unroll
    for (int j = 0; j < 2; ++j) {
        int ci = tid + j * 256;
        float sv = s_in[b * CIN + ci] * scale;
        const float* wp = weight + ((size_t)co * CIN + ci) * 9;
        #pragma unroll
        for (int t = 0; t < 9; ++t) {
            float v = wp[t] * sv;
            m[j][t] = v;
            sq += v * v;
        }
    }
    __shared__ float red[256];
    red[tid] = sq;
    __syncthreads();
    for (int off = 128; off > 0; off >>= 1) {
        if (tid < off) red[tid] += red[tid + off];
        __syncthreads();
    }
    // faithful to source: w / rsqrt(sum+eps) == w * sqrt(sum+eps)
    float dfac = sqrtf(red[0] + EPSV);
    #pragma unroll
    for (int j = 0; j < 2; ++j) {
        int ci = tid + j * 256;
        #pragma unroll
        for (int t = 0; t < 9; ++t) {
            wmod[((size_t)((b * 9 + t) * COUT) + co) * CIN + ci] =
                __float2bfloat16(m[j][t] * dfac);
        }
    }
}

// ---- kernel 3: x[b][ci][h][w] (f32) -> xpadT[b][h+1][w+1][ci] (bf16) --------
__global__ __launch_bounds__(256) void k_xpad(const float* __restrict__ x,
                                              __hip_bfloat16* __restrict__ xpad) {
    int b = blockIdx.x >> 6;
    int h = blockIdx.x & 63;
    int tid = threadIdx.x;
    __shared__ float tile[64][65];
    for (int ci0 = 0; ci0 < CIN; ci0 += 64) {
        #pragma unroll
        for (int it = 0; it < 16; ++it) {
            int idx = it * 256 + tid;
            int cil = idx >> 6, w = idx & 63;
            tile[cil][w] = x[(((size_t)b * CIN + ci0 + cil) * HH + h) * WW + w];
        }
        __syncthreads();
        #pragma unroll
        for (int it = 0; it < 16; ++it) {
            int idx = it * 256 + tid;
            int w = idx >> 6, cil = idx & 63;
            xpad[(((size_t)b * HP + h + 1) * WP + (w + 1)) * CIN + ci0 + cil] =
                __float2bfloat16(tile[cil][w]);
        }
        __syncthreads();
    }
}

// ---------------- kernel 4: conv as 9 accumulated MFMA GEMMs -----------------
// C[co, p] (128x128 tile) = sum over t, ci of wmod[b][t][co][ci] * xpadT[...][ci]
__global__ __launch_bounds__(256) void k_conv(const __hip_bfloat16* __restrict__ wmod,
                                              const __hip_bfloat16* __restrict__ xpad,
                                              float* __restrict__ out) {
    __shared__ short Albs[128 * 64];   // [co_local][ci_local] bf16, chunk-swizzled
    __shared__ short Blbs[128 * 64];   // [p_local ][ci_local] bf16, chunk-swizzled

    const int tid = threadIdx.x;
    const int b   = blockIdx.z;
    const int co0 = blockIdx.y * 128;
    const int p0  = blockIdx.x * 128;

    // staging precompute: 128 rows x 128B per tile = 1024 x 16B chunks, 4/thread
    int goffA[4], gbaseB[4], ldsoff[4];
    #pragma unroll
    for (int it = 0; it < 4; ++it) {
        int idx  = it * 256 + tid;
        int row  = idx >> 3;
        int cpos = idx & 7;
        int cdata = cpos ^ (row & 7);           // both-sides swizzle (rule #21)
        ldsoff[it] = idx * 16;                  // linear LDS dest (bytes)
        goffA[it]  = (co0 + row) * CIN + cdata * 8;
        int p = p0 + row;
        int h = p >> 6, w = p & 63;
        gbaseB[it] = ((b * HP + h) * WP + w) * CIN + cdata * 8;
    }

    const int lane = tid & 63;
    const int wid  = tid >> 6;
    const int wr   = wid >> 1, wc = wid & 1;    // 2x2 waves, 64x64 each
    const int frow = lane & 15;
    const int fk   = lane >> 4;                 // 0..3

    f32x4 acc[4][4];
    #pragma unroll
    for (int m = 0; m < 4; ++m)
        #pragma unroll
        for (int n = 0; n < 4; ++n)
            acc[m][n] = (f32x4){0.f, 0.f, 0.f, 0.f};

    for (int t = 0; t < 9; ++t) {
        int kh = t / 3, kw = t - kh * 3;
        size_t wplane = ((size_t)(b * 9 + t)) * COUT * CIN;
        int tapoff = (kh * WP + kw) * CIN;
        for (int ci0 = 0; ci0 < CIN; ci0 += 64) {
            #pragma unroll
            for (int it = 0; it < 4; ++it) {
                const __hip_bfloat16* g = wmod + wplane + (size_t)(goffA[it] + ci0);
                __builtin_amdgcn_global_load_lds(
                    (const __attribute__((address_space(1))) void*)g,
                    (__attribute__((address_space(3))) void*)((char*)Albs + ldsoff[it]),
                    16, 0, 0);
            }
            #pragma unroll
            for (int it = 0; it < 4; ++it) {
                const __hip_bfloat16* g = xpad + (size_t)(gbaseB[it] + tapoff + ci0);
                __builtin_amdgcn_global_load_lds(
                    (const __attribute__((address_space(1))) void*)g,
                    (__attribute__((address_space(3))) void*)((char*)Blbs + ldsoff[it]),
                    16, 0, 0);
            }
            __syncthreads();   // compiler drains vmcnt(0) before s_barrier

            #pragma unroll
            for (int kk = 0; kk < 2; ++kk) {
                bf16x8 af[4], bv[4];
                #pragma unroll
                for (int m = 0; m < 4; ++m) {
                    int row = wr * 64 + m * 16 + frow;
                    int byteoff = row * 128 + (((kk * 4 + fk) ^ (row & 7)) * 16);
                    af[m] = *(const bf16x8*)((const char*)Albs + byteoff);
                }
                #pragma unroll
                for (int n = 0; n < 4; ++n) {
                    int row = wc * 64 + n * 16 + frow;
                    int byteoff = row * 128 + (((kk * 4 + fk) ^ (row & 7)) * 16);
                    bv[n] = *(const bf16x8*)((const char*)Blbs + byteoff);
                }
                #pragma unroll
                for (int m = 0; m < 4; ++m)
                    #pragma unroll
                    for (int n = 0; n < 4; ++n)
                        acc[m][n] = __builtin_amdgcn_mfma_f32_16x16x32_bf16(
                            af[m], bv[n], acc[m][n], 0, 0, 0);
            }
            __syncthreads();
        }
    }

    // epilogue: C/D mapping col=lane&15 (=p), row=(lane>>4)*4+reg (=co)
    #pragma unroll
    for (int m = 0; m < 4; ++m) {
        int co = co0 + wr * 64 + m * 16 + fk * 4;
        #pragma unroll
        for (int n = 0; n < 4; ++n) {
            int p = p0 + wc * 64 + n * 16 + frow;
            #pragma unroll
            for (int j = 0; j < 4; ++j) {
                out[((size_t)(b * COUT + co + j)) * NP + p] = acc[m][n][j];
            }
        }
    }
}

// -----------------------------------------------------------------------------
extern "C" void kernel_launch(void* const* d_in, const int* in_sizes, int n_in,
                              void* d_out, int out_size, void* d_ws, size_t ws_size,
                              hipStream_t stream) {
    const float* x      = (const float*)d_in[0];
    const float* style  = (const float*)d_in[1];
    const float* weight = (const float*)d_in[2];
    const float* mod_w  = (const float*)d_in[3];
    const float* mod_b  = (const float*)d_in[4];
    float* out = (float*)d_out;

    char* ws = (char*)d_ws;
    const size_t S_OFF    = 0;                       // 8*512*4      = 16 KB
    const size_t WMOD_OFF = 16384;                   // 8*9*512*512*2 = 36 MB
    const size_t XPAD_OFF = WMOD_OFF + (size_t)B_ * 9 * COUT * CIN * 2;
    const size_t XPAD_BYTES = (size_t)B_ * HP * WP * CIN * 2;

    float*          s_buf = (float*)(ws + S_OFF);
    __hip_bfloat16* wmod  = (__hip_bfloat16*)(ws + WMOD_OFF);
    __hip_bfloat16* xpad  = (__hip_bfloat16*)(ws + XPAD_OFF);

    hipMemsetAsync(xpad, 0, XPAD_BYTES, stream);     // zero pad borders
    k_style<<<16, 256, 0, stream>>>(style, mod_w, mod_b, s_buf);
    k_xpad<<<B_ * HH, 256, 0, stream>>>(x, xpad);
    k_wmod<<<B_ * COUT, 256, 0, stream>>>(weight, s_buf, wmod);

    dim3 grid(NP / 128, COUT / 128, B_);             // 32 x 4 x 8
    k_conv<<<grid, 256, 0, stream>>>(wmod, xpad, out);
}

// Round 2
// 200.858 us; speedup vs baseline: 1.2225x; 1.2225x over previous
//
#include <hip/hip_runtime.h>
#include <hip/hip_bf16.h>
#include <stdint.h>
#include <math.h>

#define EPSV 1e-7f
#define B_   8
#define CIN  512
#define COUT 512
#define HH   64
#define WW   64
#define SS   512
#define HP   66
#define WP   66
#define NP   (HH*WW)   // 4096 spatial

typedef __attribute__((ext_vector_type(8))) short bf16x8;
typedef __attribute__((ext_vector_type(4))) float f32x4;

// ---------------- kernel 1: s = style @ mod_w^T + mod_b  (8x512) -------------
// wave-parallel: 4 lanes per output, float4 loads
__global__ __launch_bounds__(256) void k_style(const float* __restrict__ style,
                                               const float* __restrict__ mod_w,
                                               const float* __restrict__ mod_b,
                                               float* __restrict__ s_out) {
    int tid = threadIdx.x;
    int id = blockIdx.x * 64 + (tid >> 2);     // 64 blocks x 64 outputs
    int b = id >> 9, ci = id & 511, q = tid & 3;
    const float4* st = (const float4*)(style + (size_t)b * SS);
    const float4* mw = (const float4*)(mod_w + (size_t)ci * SS);
    float acc = 0.f;
    #pragma unroll
    for (int j = 0; j < 32; ++j) {
        float4 s4 = st[q * 32 + j];
        float4 w4 = mw[q * 32 + j];
        acc += s4.x * w4.x + s4.y * w4.y + s4.z * w4.z + s4.w * w4.w;
    }
    acc += __shfl_xor(acc, 1);
    acc += __shfl_xor(acc, 2);
    if (q == 0) s_out[id] = acc + mod_b[ci];
}

// -------- kernel 2: modulate + demod weights -> bf16 wmod[b][t][co][ci] ------
__global__ __launch_bounds__(256) void k_wmod(const float* __restrict__ weight,
                                              const float* __restrict__ s_in,
                                              __hip_bfloat16* __restrict__ wmod) {
    int b  = blockIdx.x >> 9;
    int co = blockIdx.x & 511;
    int tid = threadIdx.x;
    const float scale = (float)(1.0 / sqrt(4608.0));  // 1/sqrt(Cin*K*K)
    float m[2][9];
    float sq = 0.f;
    #pragma unroll
    for (int j = 0; j < 2; ++j) {
        int ci = tid + j * 256;
        float sv = s_in[b * CIN + ci] * scale;
        const float* wp = weight + ((size_t)co * CIN + ci) * 9;
        #pragma unroll
        for (int t = 0; t < 9; ++t) {
            float v = wp[t] * sv;
            m[j][t] = v;
            sq += v * v;
        }
    }
    __shared__ float red[256];
    red[tid] = sq;
    __syncthreads();
    for (int off = 128; off > 0; off >>= 1) {
        if (tid < off) red[tid] += red[tid + off];
        __syncthreads();
    }
    // faithful to source: w / rsqrt(sum+eps) == w * sqrt(sum+eps)
    float dfac = sqrtf(red[0] + EPSV);
    #pragma unroll
    for (int j = 0; j < 2; ++j) {
        int ci = tid + j * 256;
        #pragma unroll
        for (int t = 0; t < 9; ++t) {
            wmod[((size_t)((b * 9 + t) * COUT) + co) * CIN + ci] =
                __float2bfloat16(m[j][t] * dfac);
        }
    }
}

// ---- kernel 3: x[b][ci][h][w] (f32) -> xpadT[b][h+1][w+1][ci] (bf16) --------
__global__ __launch_bounds__(256) void k_xpad(const float* __restrict__ x,
                                              __hip_bfloat16* __restrict__ xpad) {
    int b = blockIdx.x >> 6;
    int h = blockIdx.x & 63;
    int tid = threadIdx.x;
    __shared__ float tile[64][65];
    for (int ci0 = 0; ci0 < CIN; ci0 += 64) {
        #pragma unroll
        for (int it = 0; it < 16; ++it) {
            int idx = it * 256 + tid;
            int cil = idx >> 6, w = idx & 63;
            tile[cil][w] = x[(((size_t)b * CIN + ci0 + cil) * HH + h) * WW + w];
        }
        __syncthreads();
        #pragma unroll
        for (int it = 0; it < 16; ++it) {
            int idx = it * 256 + tid;
            int w = idx >> 6, cil = idx & 63;
            xpad[(((size_t)b * HP + h + 1) * WP + (w + 1)) * CIN + ci0 + cil] =
                __float2bfloat16(tile[cil][w]);
        }
        __syncthreads();
    }
}

// ---------------- kernel 4: conv as deep-pipelined 256x256 MFMA GEMM ---------
// C[co, p] = sum over t(9 taps), ci(512) of wmod[b][t][co][ci] * xpadT[..][ci]
// 144 K-tiles of BK=32; 4 LDS buffers; prefetch distance 3; vmcnt(8) per tile.

#define MM(A,B,C) __builtin_amdgcn_mfma_f32_16x16x32_bf16(A,B,C,0,0,0)

#define GLDS(GP, LOFF) __builtin_amdgcn_global_load_lds( \
    (const __attribute__((address_space(1))) void*)(GP), \
    (__attribute__((address_space(3))) void*)(smem + (LOFF)), 16, 0, 0)

#define LDA(SB, M) (*(const bf16x8*)(smem + sAoff + ((SB)*16384 + (M)*1024)))
#define LDB(SB, N) (*(const bf16x8*)(smem + sBoff + ((SB)*16384 + (N)*1024)))

#define STAGE_A(KT, SB) { const int t3_ = (KT) >> 4, ci3_ = ((KT) & 15) * 32;   \
    const size_t aB_ = (size_t)(bb * 9 + t3_) * (COUT * CIN) + ci3_;            \
    GLDS(wmod + aB_ + gA0, (SB) * 16384 + ldsd);                                \
    GLDS(wmod + aB_ + gA1, (SB) * 16384 + 8192 + ldsd); }

#define STAGE_B(KT, SB) { const int t3_ = (KT) >> 4, ci3_ = ((KT) & 15) * 32;   \
    const int bO_ = ((t3_ / 3) * WP + (t3_ % 3)) * CIN + ci3_;                  \
    GLDS(xpad + bO_ + gB0, 65536 + (SB) * 16384 + ldsd);                        \
    GLDS(xpad + bO_ + gB1, 65536 + (SB) * 16384 + 8192 + ldsd); }

#define BARRIER asm volatile("s_barrier" ::: "memory")
#define LGKM0   asm volatile("s_waitcnt lgkmcnt(0)" ::: "memory")
#define VM8 asm volatile("s_waitcnt vmcnt(8)" ::: "memory");
#define VM4 asm volatile("s_waitcnt vmcnt(4)" ::: "memory");
#define VM0 asm volatile("s_waitcnt vmcnt(0)" ::: "memory");
#define VMNONE

#define MROW(M, AV) acc[M][0]=MM(AV,b0_,acc[M][0]); acc[M][1]=MM(AV,b1_,acc[M][1]); \
                    acc[M][2]=MM(AV,b2_,acc[M][2]); acc[M][3]=MM(AV,b3_,acc[M][3]);

#define KTILE(KK, SB, DOSTAGE, WAITER) {                                        \
    bf16x8 a0_=LDA(SB,0), a1_=LDA(SB,1), a2_=LDA(SB,2), a3_=LDA(SB,3);          \
    bf16x8 b0_=LDB(SB,0), b1_=LDB(SB,1), b2_=LDB(SB,2), b3_=LDB(SB,3);          \
    if (DOSTAGE) STAGE_A((KK) + 3, ((SB) + 3) & 3);                             \
    BARRIER; LGKM0;                                                             \
    __builtin_amdgcn_s_setprio(1);                                              \
    MROW(0, a0_) MROW(1, a1_) MROW(2, a2_) MROW(3, a3_)                         \
    __builtin_amdgcn_s_setprio(0);                                              \
    BARRIER;                                                                    \
    bf16x8 a4_=LDA(SB,4), a5_=LDA(SB,5), a6_=LDA(SB,6), a7_=LDA(SB,7);          \
    if (DOSTAGE) STAGE_B((KK) + 3, ((SB) + 3) & 3);                             \
    WAITER                                                                      \
    BARRIER; LGKM0;                                                             \
    __builtin_amdgcn_s_setprio(1);                                              \
    MROW(4, a4_) MROW(5, a5_) MROW(6, a6_) MROW(7, a7_)                         \
    __builtin_amdgcn_s_setprio(0);                                              \
    BARRIER;                                                                    \
}

__global__ __launch_bounds__(512, 2) void k_conv(const __hip_bfloat16* __restrict__ wmod,
                                                 const __hip_bfloat16* __restrict__ xpad,
                                                 float* __restrict__ out) {
    // LDS: A bufs 0..3 at buf*16384 (256 rows x 64B), B bufs at 65536 + buf*16384
    __shared__ __align__(16) char smem[131072];

    const int tid  = threadIdx.x;
    const int lane = tid & 63;
    const int wid  = tid >> 6;           // 8 waves
    const int wr   = wid >> 2;           // 0..1  (M: 128 rows each)
    const int wc   = wid & 3;            // 0..3  (N: 64 cols each)
    const int frow = lane & 15;
    const int fk   = lane >> 4;          // 0..3 (k-chunk of 8 bf16)
    const int bb   = blockIdx.z;
    const int co0  = blockIdx.y * 256;
    const int p0   = blockIdx.x * 256;

    // ds_read bases: row*64B + swizzled chunk; swz(row) = (row>>1)&3 = (frow>>1)&3
    const int xr    = (fk ^ ((frow >> 1) & 3)) * 16;
    const int sAoff = wr * 8192 + frow * 64 + xr;
    const int sBoff = 65536 + wc * 4096 + frow * 64 + xr;

    // staging: per wave-instr 16 rows x 64B linear LDS; global source pre-swizzled
    const int ldsd = wid * 1024 + lane * 16;
    const int srow = wid * 16 + (lane >> 2);                  // + i*128
    const int cg   = ((lane & 3) ^ ((lane >> 3) & 3)) * 8;    // chunk^swz(row), elems
    const int gA0  = (co0 + srow) * CIN + cg;
    const int gA1  = (co0 + 128 + srow) * CIN + cg;
    const int pp0  = p0 + srow;
    const int pp1  = p0 + 128 + srow;
    const int gB0  = ((bb * HP + (pp0 >> 6)) * WP + (pp0 & 63)) * CIN + cg;
    const int gB1  = ((bb * HP + (pp1 >> 6)) * WP + (pp1 & 63)) * CIN + cg;

    f32x4 acc[8][4];
    #pragma unroll
    for (int m = 0; m < 8; ++m)
        #pragma unroll
        for (int n = 0; n < 4; ++n)
            acc[m][n] = (f32x4){0.f, 0.f, 0.f, 0.f};

    // prologue: stage K-tiles 0,1,2 into bufs 0,1,2 (12 loads/thread)
    STAGE_A(0, 0) STAGE_B(0, 0)
    STAGE_A(1, 1) STAGE_B(1, 1)
    STAGE_A(2, 2) STAGE_B(2, 2)
    VM8;       // tile 0 complete (tiles 1,2 = 8 loads still in flight)
    BARRIER;

    // main loop: 144 K-tiles; tile k reads buf k&3, stages tile k+3 into (k+3)&3
    for (int k4 = 0; k4 < 140; k4 += 4) {
        KTILE(k4 + 0, 0, 1, VM8)
        KTILE(k4 + 1, 1, 1, VM8)
        KTILE(k4 + 2, 2, 1, VM8)
        KTILE(k4 + 3, 3, 1, VM8)
    }
    KTILE(140, 0, 1, VM8)     // stages tile 143
    KTILE(141, 1, 0, VM4)
    KTILE(142, 2, 0, VM0)
    KTILE(143, 3, 0, VMNONE)

    // epilogue: C/D mapping col(lane&15)=p, row=(lane>>4)*4+j = co
    #pragma unroll
    for (int m = 0; m < 8; ++m) {
        int co = co0 + wr * 128 + m * 16 + fk * 4;
        #pragma unroll
        for (int n = 0; n < 4; ++n) {
            int p = p0 + wc * 64 + n * 16 + frow;
            #pragma unroll
            for (int j = 0; j < 4; ++j)
                out[((size_t)(bb * COUT + co + j)) * NP + p] = acc[m][n][j];
        }
    }
}

// -----------------------------------------------------------------------------
extern "C" void kernel_launch(void* const* d_in, const int* in_sizes, int n_in,
                              void* d_out, int out_size, void* d_ws, size_t ws_size,
                              hipStream_t stream) {
    const float* x      = (const float*)d_in[0];
    const float* style  = (const float*)d_in[1];
    const float* weight = (const float*)d_in[2];
    const float* mod_w  = (const float*)d_in[3];
    const float* mod_b  = (const float*)d_in[4];
    float* out = (float*)d_out;

    char* ws = (char*)d_ws;
    const size_t S_OFF    = 0;                       // 8*512*4      = 16 KB
    const size_t WMOD_OFF = 16384;                   // 8*9*512*512*2 = 36 MB
    const size_t XPAD_OFF = WMOD_OFF + (size_t)B_ * 9 * COUT * CIN * 2;
    const size_t XPAD_BYTES = (size_t)B_ * HP * WP * CIN * 2;

    float*          s_buf = (float*)(ws + S_OFF);
    __hip_bfloat16* wmod  = (__hip_bfloat16*)(ws + WMOD_OFF);
    __hip_bfloat16* xpad  = (__hip_bfloat16*)(ws + XPAD_OFF);

    hipMemsetAsync(xpad, 0, XPAD_BYTES, stream);     // zero pad borders
    k_style<<<64, 256, 0, stream>>>(style, mod_w, mod_b, s_buf);
    k_xpad<<<B_ * HH, 256, 0, stream>>>(x, xpad);
    k_wmod<<<B_ * COUT, 256, 0, stream>>>(weight, s_buf, wmod);

    dim3 grid(NP / 256, COUT / 256, B_);             // 16 x 2 x 8
    k_conv<<<grid, 512, 0, stream>>>(wmod, xpad, out);
}

// Round 3
// 160.471 us; speedup vs baseline: 1.5302x; 1.2517x over previous
//
#include <hip/hip_runtime.h>
#include <hip/hip_bf16.h>
#include <stdint.h>
#include <math.h>

#define EPSV 1e-7f
#define B_   8
#define CIN  512
#define COUT 512
#define HH   64
#define WW   64
#define SS   512
#define HP   66
#define WP   66
#define NP   (HH*WW)   // 4096 spatial

typedef __attribute__((ext_vector_type(8))) short bf16x8;
typedef __attribute__((ext_vector_type(4))) float f32x4;

// ---------------- kernel 1: s = style @ mod_w^T + mod_b  (8x512) -------------
__global__ __launch_bounds__(256) void k_style(const float* __restrict__ style,
                                               const float* __restrict__ mod_w,
                                               const float* __restrict__ mod_b,
                                               float* __restrict__ s_out) {
    int tid = threadIdx.x;
    int id = blockIdx.x * 64 + (tid >> 2);     // 64 blocks x 64 outputs
    int b = id >> 9, ci = id & 511, q = tid & 3;
    const float4* st = (const float4*)(style + (size_t)b * SS);
    const float4* mw = (const float4*)(mod_w + (size_t)ci * SS);
    float acc = 0.f;
    #pragma unroll
    for (int j = 0; j < 32; ++j) {
        float4 s4 = st[q * 32 + j];
        float4 w4 = mw[q * 32 + j];
        acc += s4.x * w4.x + s4.y * w4.y + s4.z * w4.z + s4.w * w4.w;
    }
    acc += __shfl_xor(acc, 1);
    acc += __shfl_xor(acc, 2);
    if (q == 0) s_out[id] = acc + mod_b[ci];
}

// -------- kernel 2: modulate + demod weights -> bf16 wmod[b][t][co][ci] ------
// one block per co; weight row read once, all 8 batches produced
__global__ __launch_bounds__(256) void k_wmod(const float* __restrict__ weight,
                                              const float* __restrict__ s_in,
                                              __hip_bfloat16* __restrict__ wmod) {
    const int co  = blockIdx.x;              // 512 blocks
    const int tid = threadIdx.x;
    const int lane = tid & 63, wid = tid >> 6;
    const float scale = 0.014731391274719739f;   // 1/sqrt(4608)
    float wv0[9], wv1[9];
    float wsq0 = 0.f, wsq1 = 0.f;
    {
        const float* wp0 = weight + ((size_t)co * CIN + tid) * 9;
        const float* wp1 = weight + ((size_t)co * CIN + tid + 256) * 9;
        #pragma unroll
        for (int t = 0; t < 9; ++t) { wv0[t] = wp0[t]; wsq0 += wv0[t] * wv0[t]; }
        #pragma unroll
        for (int t = 0; t < 9; ++t) { wv1[t] = wp1[t]; wsq1 += wv1[t] * wv1[t]; }
    }
    float sv0[8], sv1[8], sqb[8];
    #pragma unroll
    for (int b = 0; b < 8; ++b) {
        sv0[b] = s_in[b * CIN + tid] * scale;
        sv1[b] = s_in[b * CIN + tid + 256] * scale;
        sqb[b] = sv0[b] * sv0[b] * wsq0 + sv1[b] * sv1[b] * wsq1;
    }
    #pragma unroll
    for (int b = 0; b < 8; ++b) {
        float v = sqb[b];
        #pragma unroll
        for (int off = 32; off > 0; off >>= 1) v += __shfl_xor(v, off);
        sqb[b] = v;
    }
    __shared__ float red[4][8];
    if (lane == 0) {
        #pragma unroll
        for (int b = 0; b < 8; ++b) red[wid][b] = sqb[b];
    }
    __syncthreads();
    float dfac[8];
    #pragma unroll
    for (int b = 0; b < 8; ++b)
        dfac[b] = sqrtf(red[0][b] + red[1][b] + red[2][b] + red[3][b] + EPSV);
    #pragma unroll
    for (int b = 0; b < 8; ++b) {
        #pragma unroll
        for (int t = 0; t < 9; ++t) {
            size_t rowbase = ((size_t)((b * 9 + t) * COUT) + co) * CIN;
            wmod[rowbase + tid]       = __float2bfloat16(wv0[t] * sv0[b] * dfac[b]);
            wmod[rowbase + tid + 256] = __float2bfloat16(wv1[t] * sv1[b] * dfac[b]);
        }
    }
}

// ---- kernel 3: x[b][ci][h][w] (f32) -> xpadT[b][h+1][w+1][ci] (bf16) --------
// vectorized; also writes the zero borders (memset eliminated)
__global__ __launch_bounds__(256) void k_xpad(const float* __restrict__ x,
                                              __hip_bfloat16* __restrict__ xpad) {
    const int b = blockIdx.x >> 6;
    const int h = blockIdx.x & 63;
    const int tid = threadIdx.x;
    __shared__ float tile[64][65];
    for (int ci0 = 0; ci0 < CIN; ci0 += 64) {
        #pragma unroll
        for (int it = 0; it < 4; ++it) {
            int idx = it * 256 + tid;
            int w4 = idx & 15, cil = idx >> 4;
            float4 v = *(const float4*)&x[(((size_t)b * CIN + ci0 + cil) * HH + h) * WW + 4 * w4];
            tile[cil][4 * w4 + 0] = v.x; tile[cil][4 * w4 + 1] = v.y;
            tile[cil][4 * w4 + 2] = v.z; tile[cil][4 * w4 + 3] = v.w;
        }
        __syncthreads();
        #pragma unroll
        for (int it = 0; it < 4; ++it) {
            int idx = it * 256 + tid;
            int c4 = idx & 15, w = idx >> 4;
            __hip_bfloat16 t0 = __float2bfloat16(tile[4 * c4 + 0][w]);
            __hip_bfloat16 t1 = __float2bfloat16(tile[4 * c4 + 1][w]);
            __hip_bfloat16 t2 = __float2bfloat16(tile[4 * c4 + 2][w]);
            __hip_bfloat16 t3 = __float2bfloat16(tile[4 * c4 + 3][w]);
            ushort4 pk = make_ushort4(*(unsigned short*)&t0, *(unsigned short*)&t1,
                                      *(unsigned short*)&t2, *(unsigned short*)&t3);
            *(ushort4*)&xpad[(((size_t)b * HP + h + 1) * WP + (w + 1)) * CIN + ci0 + 4 * c4] = pk;
        }
        __syncthreads();
    }
    // borders
    const size_t base = (size_t)b * HP * WP * CIN;
    const ushort4 z4 = make_ushort4(0, 0, 0, 0);
    {   // columns wp=0 and wp=65 of row hp=h+1
        int wp = (tid < 128) ? 0 : 65;
        int e  = (tid & 127) * 4;
        *(ushort4*)&xpad[base + ((size_t)(h + 1) * WP + wp) * CIN + e] = z4;
    }
    if (h == 0 || h == 63) {   // rows hp=0 / hp=65
        int hp = (h == 0) ? 0 : 65;
        for (int i = tid; i < (HP * CIN) / 4; i += 256)
            *(ushort4*)&xpad[base + (size_t)hp * WP * CIN + (size_t)i * 4] = z4;
    }
}

// ---------------- kernel 4: conv, pipelined-fragment schedule ----------------
// C[co, p] = sum over t(9 taps), ci(512) of wmod[b][t][co][ci] * xpadT[..][ci]
// 144 K-tiles BK=32; 4 LDS buffers; mid-tile publish: vmcnt(8) + 1 barrier/tile.

#define MM(A,B,C) __builtin_amdgcn_mfma_f32_16x16x32_bf16(A,B,C,0,0,0)

#define GLDS(GP, LOFF) __builtin_amdgcn_global_load_lds( \
    (const __attribute__((address_space(1))) void*)(GP), \
    (__attribute__((address_space(3))) void*)(smem + (LOFF)), 16, 0, 0)

#define LDA(SB, M) (*(const bf16x8*)(aLds + ((SB)*16384 + (M)*1024)))
#define LDB(SB, N) (*(const bf16x8*)(bLds + ((SB)*16384 + (N)*1024)))

#define STAGE_A(KT, SB) { const int t3_ = (KT) >> 4, ci3_ = ((KT) & 15) * 32;   \
    const size_t aB_ = (size_t)(bb * 9 + t3_) * (COUT * CIN) + ci3_;            \
    GLDS(wmod + aB_ + gA0, (SB) * 16384 + ldsd);                                \
    GLDS(wmod + aB_ + gA1, (SB) * 16384 + 8192 + ldsd); }

#define STAGE_B(KT, SB) { const int t3_ = (KT) >> 4, ci3_ = ((KT) & 15) * 32;   \
    const int bO_ = ((t3_ / 3) * WP + (t3_ % 3)) * CIN + ci3_;                  \
    GLDS(xpad + bO_ + gB0, 65536 + (SB) * 16384 + ldsd);                        \
    GLDS(xpad + bO_ + gB1, 65536 + (SB) * 16384 + 8192 + ldsd); }

#define BARRIER asm volatile("s_barrier" ::: "memory")
#define VM8 asm volatile("s_waitcnt vmcnt(8)" ::: "memory");
#define VM4 asm volatile("s_waitcnt vmcnt(4)" ::: "memory");
#define VM0 asm volatile("s_waitcnt vmcnt(0)" ::: "memory");
#define VMNONE

#define CCOL(N, BV) acc[0][N]=MM(ca0,BV,acc[0][N]); acc[1][N]=MM(ca1,BV,acc[1][N]); \
                    acc[2][N]=MM(ca2,BV,acc[2][N]); acc[3][N]=MM(ca3,BV,acc[3][N]);
#define XCOL(N, BV) acc[4][N]=MM(x4_,BV,acc[4][N]); acc[5][N]=MM(x5_,BV,acc[5][N]); \
                    acc[6][N]=MM(x6_,BV,acc[6][N]); acc[7][N]=MM(x7_,BV,acc[7][N]);

// Per tile KK (buffer SB=KK&3): arrive with ca0-3, cb0, cb1 already in regs.
//  top: read cb2,cb3 + A-hi(x4-7) of cur tile; stage tile KK+3.
//  cluster1 (col-major: cb0,cb1 ready; cb2,cb3 land under the first columns).
//  publish KK+1: sched fence, vmcnt(8), s_barrier.
//  read next tile's ca0-3 + nb0,nb1 (overlaps cluster2's MFMAs).
//  cluster2; rotate nb->cb.
#define KTILE3(KK, SB, DOSTAGE, WAITER, DONEXT) {                               \
    cb2 = LDB(SB, 2); cb3 = LDB(SB, 3);                                         \
    bf16x8 x4_ = LDA(SB,4), x5_ = LDA(SB,5), x6_ = LDA(SB,6), x7_ = LDA(SB,7);  \
    if (DOSTAGE) { STAGE_A((KK)+3, ((SB)+3)&3); STAGE_B((KK)+3, ((SB)+3)&3); }  \
    __builtin_amdgcn_s_setprio(1);                                              \
    CCOL(0, cb0) CCOL(1, cb1) CCOL(2, cb2) CCOL(3, cb3)                         \
    __builtin_amdgcn_s_setprio(0);                                              \
    __builtin_amdgcn_sched_barrier(0);                                          \
    WAITER                                                                      \
    BARRIER;                                                                    \
    __builtin_amdgcn_sched_barrier(0);                                          \
    if (DONEXT) { const int nsb_ = ((SB)+1)&3;                                  \
        ca0 = LDA(nsb_,0); ca1 = LDA(nsb_,1);                                   \
        ca2 = LDA(nsb_,2); ca3 = LDA(nsb_,3);                                   \
        nb0_ = LDB(nsb_,0); nb1_ = LDB(nsb_,1);                                 \
    }                                                                           \
    __builtin_amdgcn_s_setprio(1);                                              \
    XCOL(0, cb0) XCOL(1, cb1) XCOL(2, cb2) XCOL(3, cb3)                         \
    __builtin_amdgcn_s_setprio(0);                                              \
    cb0 = nb0_; cb1 = nb1_;                                                     \
}

__global__ __launch_bounds__(512, 2) void k_conv(const __hip_bfloat16* __restrict__ wmod,
                                                 const __hip_bfloat16* __restrict__ xpad,
                                                 float* __restrict__ out) {
    __shared__ __align__(16) char smem[131072];

    const int tid  = threadIdx.x;
    const int lane = tid & 63;
    const int wid  = tid >> 6;           // 8 waves
    const int wr   = wid >> 2;           // 0..1  (M: 128 rows each)
    const int wc   = wid & 3;            // 0..3  (N: 64 cols each)
    const int frow = lane & 15;
    const int fk   = lane >> 4;          // 0..3 (k-chunk of 8 bf16)

    // XCD-major decode: bid%8 = batch -> each XCD owns one batch's panels
    const int bid = blockIdx.x;
    const int bb  = bid & 7;
    const int pt  = (bid >> 3) & 15;
    const int ct  = bid >> 7;
    const int co0 = ct * 256;
    const int p0  = pt * 256;

    // ds_read bases: row*64B + swizzled chunk; swz(row) = (row>>1)&3 = (frow>>1)&3
    const int xr = (fk ^ ((frow >> 1) & 3)) * 16;
    const char* aLds = smem + (wr * 8192 + frow * 64 + xr);
    const char* bLds = smem + 65536 + (wc * 4096 + frow * 64 + xr);

    // staging: 16 rows x 64B per wave-instr, linear LDS; global source pre-swizzled
    const int ldsd = wid * 1024 + lane * 16;
    const int srow = wid * 16 + (lane >> 2);
    const int cg   = ((lane & 3) ^ ((lane >> 3) & 3)) * 8;
    const int gA0  = (co0 + srow) * CIN + cg;
    const int gA1  = (co0 + 128 + srow) * CIN + cg;
    const int pp0  = p0 + srow;
    const int pp1  = p0 + 128 + srow;
    const int gB0  = ((bb * HP + (pp0 >> 6)) * WP + (pp0 & 63)) * CIN + cg;
    const int gB1  = ((bb * HP + (pp1 >> 6)) * WP + (pp1 & 63)) * CIN + cg;

    f32x4 acc[8][4];
    #pragma unroll
    for (int m = 0; m < 8; ++m)
        #pragma unroll
        for (int n = 0; n < 4; ++n)
            acc[m][n] = (f32x4){0.f, 0.f, 0.f, 0.f};

    bf16x8 ca0, ca1, ca2, ca3, cb0, cb1, cb2, cb3, nb0_, nb1_;

    // prologue: stage K-tiles 0,1,2 into bufs 0,1,2
    STAGE_A(0, 0) STAGE_B(0, 0)
    STAGE_A(1, 1) STAGE_B(1, 1)
    STAGE_A(2, 2) STAGE_B(2, 2)
    VM8;       // tile 0 landed (A0,B0 are the 4 oldest)
    BARRIER;
    ca0 = LDA(0, 0); ca1 = LDA(0, 1); ca2 = LDA(0, 2); ca3 = LDA(0, 3);
    cb0 = LDB(0, 0); cb1 = LDB(0, 1);

    for (int k4 = 0; k4 < 140; k4 += 4) {
        KTILE3(k4 + 0, 0, 1, VM8, 1)
        KTILE3(k4 + 1, 1, 1, VM8, 1)
        KTILE3(k4 + 2, 2, 1, VM8, 1)
        KTILE3(k4 + 3, 3, 1, VM8, 1)
    }
    KTILE3(140, 0, 1, VM8, 1)     // stages tile 143; publishes 141
    KTILE3(141, 1, 0, VM4, 1)     // publishes 142
    KTILE3(142, 2, 0, VM0, 1)     // publishes 143
    KTILE3(143, 3, 0, VMNONE, 0)

    // epilogue: C/D mapping col(lane&15)=p, row=(lane>>4)*4+j = co
    #pragma unroll
    for (int m = 0; m < 8; ++m) {
        int co = co0 + wr * 128 + m * 16 + fk * 4;
        #pragma unroll
        for (int n = 0; n < 4; ++n) {
            int p = p0 + wc * 64 + n * 16 + frow;
            #pragma unroll
            for (int j = 0; j < 4; ++j)
                out[((size_t)(bb * COUT + co + j)) * NP + p] = acc[m][n][j];
        }
    }
}

// -----------------------------------------------------------------------------
extern "C" void kernel_launch(void* const* d_in, const int* in_sizes, int n_in,
                              void* d_out, int out_size, void* d_ws, size_t ws_size,
                              hipStream_t stream) {
    const float* x      = (const float*)d_in[0];
    const float* style  = (const float*)d_in[1];
    const float* weight = (const float*)d_in[2];
    const float* mod_w  = (const float*)d_in[3];
    const float* mod_b  = (const float*)d_in[4];
    float* out = (float*)d_out;

    char* ws = (char*)d_ws;
    const size_t S_OFF    = 0;                       // 8*512*4       = 16 KB
    const size_t WMOD_OFF = 16384;                   // 8*9*512*512*2 = 36 MB
    const size_t XPAD_OFF = WMOD_OFF + (size_t)B_ * 9 * COUT * CIN * 2;

    float*          s_buf = (float*)(ws + S_OFF);
    __hip_bfloat16* wmod  = (__hip_bfloat16*)(ws + WMOD_OFF);
    __hip_bfloat16* xpad  = (__hip_bfloat16*)(ws + XPAD_OFF);

    k_style<<<64, 256, 0, stream>>>(style, mod_w, mod_b, s_buf);
    k_xpad<<<B_ * HH, 256, 0, stream>>>(x, xpad);      // borders fused, no memset
    k_wmod<<<512, 256, 0, stream>>>(weight, s_buf, wmod);

    k_conv<<<256, 512, 0, stream>>>(wmod, xpad, out);
}